// Round 2
// baseline (384.048 us; speedup 1.0000x reference)
//
#include <hip/hip_runtime.h>
#include <math.h>

// Problem constants
#define N_Q    32768
#define N_E    262144
// dims: IN=EMB=192, concat=384, 2*HID=384, BOT=192, PREDH=192, OUT=4

typedef _Float16 half8 __attribute__((ext_vector_type(8)));
typedef _Float16 half4v __attribute__((ext_vector_type(4)));
typedef float f32x4 __attribute__((ext_vector_type(4)));

// A&S 7.1.25 erf (|eps|<=2.5e-5, invisible under f16 storage rounding 5e-4).
__device__ __forceinline__ float gelu_f(float x) {
    float ax = fabsf(x);
    float t = __builtin_amdgcn_rcpf(fmaf(0.33269070724668f, ax, 1.0f));
    float poly = t * fmaf(t, fmaf(t, 0.7478556f, -0.0958798f), 0.3480242f);
    float e = exp2f(-0.72134752044448f * ax * ax);
    float u = fmaf(-poly, e, 1.0f);          // erf(z)
    return 0.5f * fmaf(ax, u, x);
}

// ---------------- sincos embedding -> f16 (hw sin/cos on revolutions) ----------------
__global__ __launch_bounds__(256) void embed_kernel(const float* __restrict__ qpos,
                                                    _Float16* __restrict__ qe) {
    int gid = blockIdx.x * 256 + threadIdx.x;   // covers N_Q*96: (q, d, i)
    int q = gid / 96, r = gid - q * 96;
    int d = r >> 5, i = r & 31;
    float omega = exp2f(-(float)i * 0.41524101186092029f);  // log2(10000)/32
    float arg = qpos[q * 3 + d] * omega;
    float rev = arg * 0.15915494309189535f;                  // radians -> revolutions
    rev = rev - floorf(rev);
    float s = __builtin_amdgcn_sinf(rev);
    float c = __builtin_amdgcn_cosf(rev);
    int base = q * 192 + d * 64 + i;
    qe[base] = (_Float16)s;
    qe[base + 32] = (_Float16)c;
}

// ---------------- pack W[K][N] fp32 -> fragment-order f16 (all 5 mats, one launch) ----
// Per (n_tile, ks) a 1KB block; lane l holds B[k=ks*32+(l>>4)*8+j][n=n_tile*16+(l&15)]
// (This is simultaneously the A-operand fragment of W^T -- used as 1st mfma operand.)
__device__ __forceinline__ void pack_one(const float* __restrict__ W,
                                         _Float16* __restrict__ Wp,
                                         int K, int N, int blk0, int tid) {
    int u = blk0 * 256 + tid;                   // one half8 per thread
    if (u * 8 >= K * N) return;
    int l = u & 63, blk = u >> 6;
    int nks = K >> 5;
    int ntile = blk / nks, ks = blk - ntile * nks;
    int n = ntile * 16 + (l & 15);
    int k0 = ks * 32 + (l >> 4) * 8;
    half8 v;
    #pragma unroll
    for (int j = 0; j < 8; ++j) v[j] = (_Float16)W[(size_t)(k0 + j) * N + n];
    *(half8*)(Wp + (size_t)u * 8) = v;
}

__global__ __launch_bounds__(256) void pack_all_kernel(
    const float* __restrict__ pw,  _Float16* __restrict__ WpP,
    const float* __restrict__ m0,  _Float16* __restrict__ Wp0,
    const float* __restrict__ m1,  _Float16* __restrict__ Wp1,
    const float* __restrict__ m2,  _Float16* __restrict__ Wp2,
    const float* __restrict__ hw,  _Float16* __restrict__ WpH) {
    int b = blockIdx.x, t = threadIdx.x;
    if      (b < 18)  pack_one(pw, WpP, 192, 192, b,        t);
    else if (b < 90)  pack_one(m0, Wp0, 384, 384, b - 18,   t);
    else if (b < 162) pack_one(m1, Wp1, 384, 384, b - 90,   t);
    else if (b < 198) pack_one(m2, Wp2, 384, 192, b - 162,  t);
    else              pack_one(hw, WpH, 192, 192, b - 198,  t);
}

// ---------------- proj: xf = f16(x @ proj_w + proj_b), via MFMA (swapped ops) --------
// mfma(Wfrag, hfrag) = (h@W)^T : lane holds out[m=ln][n = base + lq*4 + r]
#define PK 200   // hA row stride (f16), 400 B

__global__ __launch_bounds__(256, 2) void proj_mfma_kernel(
    const float* __restrict__ x, const _Float16* __restrict__ Wp,
    const float* __restrict__ bias, _Float16* __restrict__ xf)
{
    __shared__ _Float16 hA[64 * PK];   // 25600 B
    const int t = threadIdx.x;
    const int r0 = blockIdx.x * 64;
    const int lane = t & 63;
    const int w = t >> 6;
    const int ln = lane & 15, lq = lane >> 4;

    #pragma unroll
    for (int i = 0; i < 12; ++i) {                 // 3072 float4s
        int idx = t + 256 * i;
        int r = idx / 48, c4 = idx - r * 48;
        float4 v = ((const float4*)(x + (size_t)(r0 + r) * 192))[c4];
        half4v hv; hv[0] = (_Float16)v.x; hv[1] = (_Float16)v.y;
        hv[2] = (_Float16)v.z; hv[3] = (_Float16)v.w;
        *(half4v*)(hA + r * PK + c4 * 4) = hv;
    }
    __syncthreads();

    f32x4 acc[4][3];
    #pragma unroll
    for (int nt = 0; nt < 3; ++nt) {
        f32x4 bv = *(const f32x4*)(bias + w * 48 + nt * 16 + lq * 4);
        #pragma unroll
        for (int mt = 0; mt < 4; ++mt) acc[mt][nt] = bv;
    }
    #pragma unroll 2
    for (int ks = 0; ks < 6; ++ks) {
        half8 a[4], bf[3];
        #pragma unroll
        for (int mt = 0; mt < 4; ++mt)
            a[mt] = *(const half8*)(hA + (mt * 16 + ln) * PK + ks * 32 + lq * 8);
        #pragma unroll
        for (int nt = 0; nt < 3; ++nt)
            bf[nt] = *(const half8*)(Wp + (size_t)(((w * 3 + nt) * 6 + ks) * 512 + lane * 8));
        #pragma unroll
        for (int nt = 0; nt < 3; ++nt)
            #pragma unroll
            for (int mt = 0; mt < 4; ++mt)
                acc[mt][nt] = __builtin_amdgcn_mfma_f32_16x16x32_f16(bf[nt], a[mt], acc[mt][nt], 0, 0, 0);
    }
    // lane holds xf[m = mt*16+ln][n = w*48 + nt*16 + lq*4 + r]: packed b64 stores
    #pragma unroll
    for (int mt = 0; mt < 4; ++mt)
        #pragma unroll
        for (int nt = 0; nt < 3; ++nt) {
            half4v hv;
            #pragma unroll
            for (int r = 0; r < 4; ++r) hv[r] = (_Float16)acc[mt][nt][r];
            *(half4v*)(xf + (size_t)(r0 + mt * 16 + ln) * 192 + w * 48 + nt * 16 + lq * 4) = hv;
        }
}

// ---------------- fused edge MLP via f16 MFMA, 512 threads / 8 waves ----------------
#define PADK 392   // hA row stride in f16 elements (784 B); row ≡ 4 dwords mod 32
#define H2S  196   // h2 (f32 view) row stride; 196 ≡ 4 mod 32 -> conflict-free b128

__global__ __launch_bounds__(512, 6) void edge_mlp_kernel(
    const _Float16* __restrict__ xf, const _Float16* __restrict__ qe,
    const int* __restrict__ edges,
    const _Float16* __restrict__ Wp0, const float* __restrict__ b0,
    const _Float16* __restrict__ Wp1, const float* __restrict__ b1,
    const _Float16* __restrict__ Wp2, const float* __restrict__ b2,
    float* __restrict__ seg, float* __restrict__ cnt)
{
    __shared__ _Float16 hA[64 * PADK];   // 50176 B; aliased as f32 h2[64][H2S] later
    __shared__ int qi[64];
    float* h2 = (float*)hA;

    const int t = threadIdx.x;
    const int e0 = blockIdx.x * 64;
    const int lane = t & 63;
    const int w = t >> 6;                // 0..7
    const int ln = lane & 15;            // MFMA col index (m after swap)
    const int lq = lane >> 4;            // quad (n sub-offset after swap)

    if (t < 64) qi[t] = edges[2 * (e0 + t)];

    // ---- gather concat(xf[g], qe[q]): thread t owns edge m=t>>3, chunk lane t&7 ----
    {
        const int m = t >> 3;            // 0..63
        const int cl = t & 7;
        int2 eg = ((const int2*)edges)[e0 + m];     // {qidx, gidx}
        const half8* xsrc = (const half8*)(xf + (size_t)eg.y * 192) + cl;
        const half8* qsrc = (const half8*)(qe + (size_t)eg.x * 192) + cl;
        half8* dst = (half8*)(hA + m * PADK + cl * 8);
        #pragma unroll
        for (int i = 0; i < 3; ++i) dst[i * 8] = xsrc[i * 8];          // cols 0..191
        #pragma unroll
        for (int i = 0; i < 3; ++i) dst[24 + i * 8] = qsrc[i * 8];     // cols 192..383
    }
    __syncthreads();

    // ---- layers 0,1: 384 -> 384, gelu, in-place. wave w owns 48-col output slice ----
    #pragma unroll 1
    for (int L = 0; L < 2; ++L) {
        const _Float16* __restrict__ Wp = L ? Wp1 : Wp0;
        const float* __restrict__ bias = L ? b1 : b0;

        f32x4 acc[4][3];
        #pragma unroll
        for (int nt = 0; nt < 3; ++nt) {
            f32x4 bv = *(const f32x4*)(bias + w * 48 + nt * 16 + lq * 4);
            #pragma unroll
            for (int mt = 0; mt < 4; ++mt) acc[mt][nt] = bv;
        }
        #pragma unroll 2
        for (int ks = 0; ks < 12; ++ks) {
            half8 a[4], bf[3];
            #pragma unroll
            for (int mt = 0; mt < 4; ++mt)
                a[mt] = *(const half8*)(hA + (mt * 16 + ln) * PADK + ks * 32 + lq * 8);
            #pragma unroll
            for (int nt = 0; nt < 3; ++nt)
                bf[nt] = *(const half8*)(Wp + (size_t)(((w * 3 + nt) * 12 + ks) * 512 + lane * 8));
            #pragma unroll
            for (int nt = 0; nt < 3; ++nt)
                #pragma unroll
                for (int mt = 0; mt < 4; ++mt)
                    acc[mt][nt] = __builtin_amdgcn_mfma_f32_16x16x32_f16(bf[nt], a[mt], acc[mt][nt], 0, 0, 0);
        }
        __syncthreads();   // all waves done reading hA
        // lane holds h[m = mt*16+ln][n = w*48 + nt*16 + lq*4 + r] -> packed b64 writes
        #pragma unroll
        for (int mt = 0; mt < 4; ++mt)
            #pragma unroll
            for (int nt = 0; nt < 3; ++nt) {
                half4v hv;
                #pragma unroll
                for (int r = 0; r < 4; ++r) hv[r] = (_Float16)gelu_f(acc[mt][nt][r]);
                *(half4v*)(hA + (mt * 16 + ln) * PADK + w * 48 + nt * 16 + lq * 4) = hv;
            }
        __syncthreads();
    }

    // ---- layer 2: 384 -> 192. wave w: n-slice (w&3)*48, m-half (w>>2)*32 ----
    {
        const int n0 = (w & 3) * 48;
        const int mh = (w >> 2) * 2;                 // physical m-tile base
        f32x4 acc[2][3];
        #pragma unroll
        for (int nt = 0; nt < 3; ++nt) {
            f32x4 bv = *(const f32x4*)(b2 + n0 + nt * 16 + lq * 4);
            #pragma unroll
            for (int mt = 0; mt < 2; ++mt) acc[mt][nt] = bv;
        }
        #pragma unroll 2
        for (int ks = 0; ks < 12; ++ks) {
            half8 a[2], bf[3];
            #pragma unroll
            for (int mt = 0; mt < 2; ++mt)
                a[mt] = *(const half8*)(hA + ((mh + mt) * 16 + ln) * PADK + ks * 32 + lq * 8);
            #pragma unroll
            for (int nt = 0; nt < 3; ++nt)
                bf[nt] = *(const half8*)(Wp2 + (size_t)((((w & 3) * 3 + nt) * 12 + ks) * 512 + lane * 8));
            #pragma unroll
            for (int nt = 0; nt < 3; ++nt)
                #pragma unroll
                for (int mt = 0; mt < 2; ++mt)
                    acc[mt][nt] = __builtin_amdgcn_mfma_f32_16x16x32_f16(bf[nt], a[mt], acc[mt][nt], 0, 0, 0);
        }
        __syncthreads();   // all waves done reading hA; safe to overwrite as h2
        // lane holds h2[m = (mh+mt)*16+ln][n = n0 + nt*16 + lq*4 + r] -> b128 writes
        #pragma unroll
        for (int mt = 0; mt < 2; ++mt)
            #pragma unroll
            for (int nt = 0; nt < 3; ++nt)
                *(f32x4*)(h2 + ((mh + mt) * 16 + ln) * H2S + n0 + nt * 16 + lq * 4) = acc[mt][nt];
        __syncthreads();
    }

    // ---- segment reduce within block (qidx sorted), 2 row-halves, then atomics ----
    if (t < 384) {
        int half_ = t >= 192;
        int col = t - half_ * 192;
        int mlo = half_ * 32, mhi = mlo + 32;
        float a = 0.0f;
        for (int m = mlo; m < mhi; ++m) {
            a += h2[m * H2S + col];
            if (m == mhi - 1 || qi[m + 1] != qi[m]) {
                atomicAdd(&seg[(size_t)qi[m] * 192 + col], a);
                a = 0.0f;
            }
        }
    } else if (t < 386) {
        int half_ = t - 384;
        int mlo = half_ * 32, mhi = mlo + 32;
        float run = 1.0f;
        for (int m = mlo + 1; m < mhi; ++m) {
            if (qi[m] != qi[m - 1]) { atomicAdd(&cnt[qi[m - 1]], run); run = 1.0f; }
            else run += 1.0f;
        }
        atomicAdd(&cnt[qi[mhi - 1]], run);
    }
}

// ---------------- head: m = seg/max(cnt,1); out = gelu(m@W0+b0)@W1+b1 ----------------
#define PSK 196   // ps row stride (f32)

__global__ __launch_bounds__(256, 2) void head_kernel(
    const float* __restrict__ seg, const float* __restrict__ cnt,
    const _Float16* __restrict__ Wp0, const float* __restrict__ b0,
    const float* __restrict__ w1, const float* __restrict__ b1,
    float* __restrict__ out)
{
    __shared__ _Float16 hA[64 * PK];     // 25600 B
    __shared__ float ps[64 * PSK];       // 50176 B
    __shared__ float w1s[192 * 4];
    __shared__ float invc[64];
    const int t = threadIdx.x;
    const int r0 = blockIdx.x * 64;
    const int lane = t & 63;
    const int w = t >> 6;
    const int ln = lane & 15, lq = lane >> 4;

    if (t < 64) invc[t] = 1.0f / fmaxf(cnt[r0 + t], 1.0f);
    if (t < 192) ((float4*)w1s)[t] = ((const float4*)w1)[t];
    __syncthreads();

    #pragma unroll
    for (int i = 0; i < 12; ++i) {
        int idx = t + 256 * i;
        int r = idx / 48, c4 = idx - r * 48;
        float inv = invc[r];
        float4 v = ((const float4*)(seg + (size_t)(r0 + r) * 192))[c4];
        half4v hv; hv[0] = (_Float16)(v.x * inv); hv[1] = (_Float16)(v.y * inv);
        hv[2] = (_Float16)(v.z * inv); hv[3] = (_Float16)(v.w * inv);
        *(half4v*)(hA + r * PK + c4 * 4) = hv;
    }
    __syncthreads();

    f32x4 acc[4][3];
    #pragma unroll
    for (int nt = 0; nt < 3; ++nt) {
        f32x4 bv = *(const f32x4*)(b0 + w * 48 + nt * 16 + lq * 4);
        #pragma unroll
        for (int mt = 0; mt < 4; ++mt) acc[mt][nt] = bv;
    }
    #pragma unroll 2
    for (int ks = 0; ks < 6; ++ks) {
        half8 a[4], bf[3];
        #pragma unroll
        for (int mt = 0; mt < 4; ++mt)
            a[mt] = *(const half8*)(hA + (mt * 16 + ln) * PK + ks * 32 + lq * 8);
        #pragma unroll
        for (int nt = 0; nt < 3; ++nt)
            bf[nt] = *(const half8*)(Wp0 + (size_t)(((w * 3 + nt) * 6 + ks) * 512 + lane * 8));
        #pragma unroll
        for (int nt = 0; nt < 3; ++nt)
            #pragma unroll
            for (int mt = 0; mt < 4; ++mt)
                acc[mt][nt] = __builtin_amdgcn_mfma_f32_16x16x32_f16(bf[nt], a[mt], acc[mt][nt], 0, 0, 0);
    }
    // lane holds ps[m = mt*16+ln][n = w*48 + nt*16 + lq*4 + r] -> b128 LDS writes
    #pragma unroll
    for (int mt = 0; mt < 4; ++mt)
        #pragma unroll
        for (int nt = 0; nt < 3; ++nt) {
            f32x4 g;
            #pragma unroll
            for (int r = 0; r < 4; ++r) g[r] = gelu_f(acc[mt][nt][r]);
            *(f32x4*)(ps + (mt * 16 + ln) * PSK + w * 48 + nt * 16 + lq * 4) = g;
        }
    __syncthreads();

    // layer1: 192 -> 4, one thread per (row, out-col)
    {
        int r = t >> 2, oo = t & 3;
        float a = b1[oo];
        for (int k = 0; k < 192; ++k)
            a = fmaf(ps[r * PSK + k], w1s[k * 4 + oo], a);
        out[(size_t)(r0 + r) * 4 + oo] = a;
    }
}

extern "C" void kernel_launch(void* const* d_in, const int* in_sizes, int n_in,
                              void* d_out, int out_size, void* d_ws, size_t ws_size,
                              hipStream_t stream) {
    (void)in_sizes; (void)n_in; (void)out_size; (void)ws_size;
    const float* x       = (const float*)d_in[0];
    const float* qpos    = (const float*)d_in[1];
    const int*   edges   = (const int*)d_in[2];
    const float* proj_w  = (const float*)d_in[3];
    const float* proj_b  = (const float*)d_in[4];
    const float* msg0_w  = (const float*)d_in[5];
    const float* msg0_b  = (const float*)d_in[6];
    const float* msg1_w  = (const float*)d_in[7];
    const float* msg1_b  = (const float*)d_in[8];
    const float* msg2_w  = (const float*)d_in[9];
    const float* msg2_b  = (const float*)d_in[10];
    const float* pred0_w = (const float*)d_in[11];
    const float* pred0_b = (const float*)d_in[12];
    const float* pred1_w = (const float*)d_in[13];
    const float* pred1_b = (const float*)d_in[14];
    float* out = (float*)d_out;

    // ws layout (bytes):
    //  xf  f16: 12582912                    @ 0
    //  qe  f16: 12582912                    @ 12582912
    //  seg f32: 25165824                    @ 25165824
    //  cnt f32: 131072                      @ 50331648
    //  Wp0 f16: 294912                      @ 50462720
    //  Wp1 f16: 294912                      @ 50757632
    //  Wp2 f16: 147456                      @ 51052544
    //  WpP f16: 73728                       @ 51200000
    //  WpH f16: 73728                       @ 51273728
    char* ws = (char*)d_ws;
    _Float16* xf  = (_Float16*)(ws);
    _Float16* qe  = (_Float16*)(ws + 12582912);
    float*    seg = (float*)(ws + 25165824);
    float*    cnt = (float*)(ws + 50331648);
    _Float16* Wp0 = (_Float16*)(ws + 50462720);
    _Float16* Wp1 = (_Float16*)(ws + 50757632);
    _Float16* Wp2 = (_Float16*)(ws + 51052544);
    _Float16* WpP = (_Float16*)(ws + 51200000);
    _Float16* WpH = (_Float16*)(ws + 51273728);

    hipMemsetAsync(seg, 0, 25165824 + 131072, stream);   // seg + cnt
    embed_kernel<<<12288, 256, 0, stream>>>(qpos, qe);   // 32768*96/256
    pack_all_kernel<<<216, 256, 0, stream>>>(proj_w, WpP, msg0_w, Wp0,
                                             msg1_w, Wp1, msg2_w, Wp2,
                                             pred0_w, WpH);
    proj_mfma_kernel<<<512, 256, 0, stream>>>(x, WpP, proj_b, xf);
    edge_mlp_kernel<<<4096, 512, 0, stream>>>(xf, qe, edges,
                                              Wp0, msg0_b, Wp1, msg1_b, Wp2, msg2_b,
                                              seg, cnt);
    head_kernel<<<512, 256, 0, stream>>>(seg, cnt, WpH, pred0_b,
                                         pred1_w, pred1_b, out);
}

// Round 3
// 345.912 us; speedup vs baseline: 1.1102x; 1.1102x over previous
//
#include <hip/hip_runtime.h>
#include <math.h>

// Problem constants
#define N_Q    32768
#define N_E    262144
// dims: IN=EMB=192, concat=384, 2*HID=384, BOT=192, PREDH=192, OUT=4
//
// Factorization: layer0 of the edge MLP is linear in the concat ->
//   h0(e) = gelu( pg[gidx(e)] + pq[qidx(e)] )
//   pg = x @ (proj_w @ W0_top) + (proj_b @ W0_top + msg0_b)   (per grid point)
//   pq = sincos(qpos) @ W0_bot                                 (per query)
// xf / qe are never materialized; edge kernel runs only layers 1 and 2.

typedef _Float16 half8 __attribute__((ext_vector_type(8)));
typedef _Float16 half4v __attribute__((ext_vector_type(4)));
typedef float f32x4 __attribute__((ext_vector_type(4)));

// A&S 7.1.25 erf (|eps|<=2.5e-5, invisible under f16 storage rounding 5e-4).
__device__ __forceinline__ float gelu_f(float x) {
    float ax = fabsf(x);
    float t = __builtin_amdgcn_rcpf(fmaf(0.33269070724668f, ax, 1.0f));
    float poly = t * fmaf(t, fmaf(t, 0.7478556f, -0.0958798f), 0.3480242f);
    float e = exp2f(-0.72134752044448f * ax * ax);
    float u = fmaf(-poly, e, 1.0f);          // erf(z)
    return 0.5f * fmaf(ax, u, x);
}

// ---------------- prep: Wc = proj_w @ W0_top (f32), bc = proj_b @ W0_top + b0 --------
__global__ __launch_bounds__(256) void prep_kernel(
    const float* __restrict__ proj_w, const float* __restrict__ proj_b,
    const float* __restrict__ msg0_w, const float* __restrict__ msg0_b,
    float* __restrict__ Wc, float* __restrict__ bc)
{
    int gid = blockIdx.x * 256 + threadIdx.x;
    if (gid < 73728) {                       // 192*384
        int j = gid / 384, n = gid - j * 384;
        float a = 0.0f;
        for (int k = 0; k < 192; ++k)
            a = fmaf(proj_w[j * 192 + k], msg0_w[k * 384 + n], a);
        Wc[gid] = a;
    } else if (gid < 73728 + 384) {
        int n = gid - 73728;
        float a = msg0_b[n];
        for (int k = 0; k < 192; ++k)
            a = fmaf(proj_b[k], msg0_w[k * 384 + n], a);
        bc[n] = a;
    }
}

// ---------------- pack W[K][N] fp32 -> fragment-order f16 ----------------------------
// Per (n_tile, ks) a 1KB block; lane l holds W[k=ks*32+(l>>4)*8+j][n=n_tile*16+(l&15)]
__device__ __forceinline__ void pack_one(const float* __restrict__ W,
                                         _Float16* __restrict__ Wp,
                                         int K, int N, int blk0, int tid) {
    int u = blk0 * 256 + tid;                   // one half8 per thread
    if (u * 8 >= K * N) return;
    int l = u & 63, blk = u >> 6;
    int nks = K >> 5;
    int ntile = blk / nks, ks = blk - ntile * nks;
    int n = ntile * 16 + (l & 15);
    int k0 = ks * 32 + (l >> 4) * 8;
    half8 v;
    #pragma unroll
    for (int j = 0; j < 8; ++j) v[j] = (_Float16)W[(size_t)(k0 + j) * N + n];
    *(half8*)(Wp + (size_t)u * 8) = v;
}

__global__ __launch_bounds__(256) void pack_all_kernel(
    const float* __restrict__ Wc,  _Float16* __restrict__ WpC,
    const float* __restrict__ m0,  _Float16* __restrict__ WpQ,
    const float* __restrict__ m1,  _Float16* __restrict__ Wp1,
    const float* __restrict__ m2,  _Float16* __restrict__ Wp2,
    const float* __restrict__ hw,  _Float16* __restrict__ WpH) {
    int b = blockIdx.x, t = threadIdx.x;
    if      (b < 36)  pack_one(Wc,          WpC, 192, 384, b,       t);
    else if (b < 72)  pack_one(m0 + 73728,  WpQ, 192, 384, b - 36,  t);   // W0_bot
    else if (b < 144) pack_one(m1,          Wp1, 384, 384, b - 72,  t);
    else if (b < 180) pack_one(m2,          Wp2, 384, 192, b - 144, t);
    else              pack_one(hw,          WpH, 192, 192, b - 180, t);
}

// ---------------- pg: x(f32) @ WpC + bc -> f16 (32768 x 384), swapped-operand MFMA ---
// lane holds out[m = mt*16+ln][n = w*96 + nt*16 + lq*4 + r]
#define PK 200   // hA row stride (f16), 400 B

__global__ __launch_bounds__(256, 2) void pg_kernel(
    const float* __restrict__ x, const _Float16* __restrict__ WpC,
    const float* __restrict__ bc, _Float16* __restrict__ pg)
{
    __shared__ _Float16 hA[64 * PK];   // 25600 B
    const int t = threadIdx.x;
    const int r0 = blockIdx.x * 64;
    const int lane = t & 63;
    const int w = t >> 6;
    const int ln = lane & 15, lq = lane >> 4;

    #pragma unroll
    for (int i = 0; i < 12; ++i) {                 // 3072 float4s
        int idx = t + 256 * i;
        int r = idx / 48, c4 = idx - r * 48;
        float4 v = ((const float4*)(x + (size_t)(r0 + r) * 192))[c4];
        half4v hv; hv[0] = (_Float16)v.x; hv[1] = (_Float16)v.y;
        hv[2] = (_Float16)v.z; hv[3] = (_Float16)v.w;
        *(half4v*)(hA + r * PK + c4 * 4) = hv;
    }
    __syncthreads();

    f32x4 acc[4][6];
    #pragma unroll
    for (int nt = 0; nt < 6; ++nt) {
        f32x4 bv = *(const f32x4*)(bc + w * 96 + nt * 16 + lq * 4);
        #pragma unroll
        for (int mt = 0; mt < 4; ++mt) acc[mt][nt] = bv;
    }
    #pragma unroll 2
    for (int ks = 0; ks < 6; ++ks) {
        half8 a[4], bf[6];
        #pragma unroll
        for (int mt = 0; mt < 4; ++mt)
            a[mt] = *(const half8*)(hA + (mt * 16 + ln) * PK + ks * 32 + lq * 8);
        #pragma unroll
        for (int nt = 0; nt < 6; ++nt)
            bf[nt] = *(const half8*)(WpC + (size_t)(((w * 6 + nt) * 6 + ks) * 512 + lane * 8));
        #pragma unroll
        for (int nt = 0; nt < 6; ++nt)
            #pragma unroll
            for (int mt = 0; mt < 4; ++mt)
                acc[mt][nt] = __builtin_amdgcn_mfma_f32_16x16x32_f16(bf[nt], a[mt], acc[mt][nt], 0, 0, 0);
    }
    #pragma unroll
    for (int mt = 0; mt < 4; ++mt)
        #pragma unroll
        for (int nt = 0; nt < 6; ++nt) {
            half4v hv;
            #pragma unroll
            for (int r = 0; r < 4; ++r) hv[r] = (_Float16)acc[mt][nt][r];
            *(half4v*)(pg + (size_t)(r0 + mt * 16 + ln) * 384 + w * 96 + nt * 16 + lq * 4) = hv;
        }
}

// ---------------- pq: sincos-embed fused GEMM: embed(qpos) @ WpQ -> f16 --------------
__global__ __launch_bounds__(256, 2) void pq_kernel(
    const float* __restrict__ qpos, const _Float16* __restrict__ WpQ,
    _Float16* __restrict__ pq)
{
    __shared__ _Float16 hA[64 * PK];   // 25600 B
    const int t = threadIdx.x;
    const int r0 = blockIdx.x * 64;
    const int lane = t & 63;
    const int w = t >> 6;
    const int ln = lane & 15, lq = lane >> 4;

    // embed 64 rows x 192 cols directly into LDS (hw sin/cos on revolutions)
    #pragma unroll
    for (int it = 0; it < 24; ++it) {
        int g2 = t + 256 * it;                   // 6144 = 64*96
        int r = g2 / 96, rem = g2 - r * 96;
        int d = rem >> 5, i = rem & 31;
        float omega = exp2f(-(float)i * 0.41524101186092029f);  // log2(10000)/32
        float arg = qpos[(size_t)(r0 + r) * 3 + d] * omega;
        float rev = arg * 0.15915494309189535f;
        rev = rev - floorf(rev);
        hA[r * PK + d * 64 + i]      = (_Float16)__builtin_amdgcn_sinf(rev);
        hA[r * PK + d * 64 + 32 + i] = (_Float16)__builtin_amdgcn_cosf(rev);
    }
    __syncthreads();

    f32x4 acc[4][6];
    #pragma unroll
    for (int nt = 0; nt < 6; ++nt)
        #pragma unroll
        for (int mt = 0; mt < 4; ++mt) acc[mt][nt] = (f32x4){0.f, 0.f, 0.f, 0.f};
    #pragma unroll 2
    for (int ks = 0; ks < 6; ++ks) {
        half8 a[4], bf[6];
        #pragma unroll
        for (int mt = 0; mt < 4; ++mt)
            a[mt] = *(const half8*)(hA + (mt * 16 + ln) * PK + ks * 32 + lq * 8);
        #pragma unroll
        for (int nt = 0; nt < 6; ++nt)
            bf[nt] = *(const half8*)(WpQ + (size_t)(((w * 6 + nt) * 6 + ks) * 512 + lane * 8));
        #pragma unroll
        for (int nt = 0; nt < 6; ++nt)
            #pragma unroll
            for (int mt = 0; mt < 4; ++mt)
                acc[mt][nt] = __builtin_amdgcn_mfma_f32_16x16x32_f16(bf[nt], a[mt], acc[mt][nt], 0, 0, 0);
    }
    #pragma unroll
    for (int mt = 0; mt < 4; ++mt)
        #pragma unroll
        for (int nt = 0; nt < 6; ++nt) {
            half4v hv;
            #pragma unroll
            for (int r = 0; r < 4; ++r) hv[r] = (_Float16)acc[mt][nt][r];
            *(half4v*)(pq + (size_t)(r0 + mt * 16 + ln) * 384 + w * 96 + nt * 16 + lq * 4) = hv;
        }
}

// ---------------- fused edge MLP (layers 1,2 only) via f16 MFMA, 512 thr / 8 waves ---
#define PADK 392   // hA row stride in f16 elements (784 B)
#define H2S  196   // h2 (f32 view) row stride; conflict-free b128

__global__ __launch_bounds__(512, 6) void edge_mlp_kernel(
    const _Float16* __restrict__ pg, const _Float16* __restrict__ pq,
    const int* __restrict__ edges,
    const _Float16* __restrict__ Wp1, const float* __restrict__ b1,
    const _Float16* __restrict__ Wp2, const float* __restrict__ b2,
    float* __restrict__ seg, float* __restrict__ cnt)
{
    __shared__ _Float16 hA[64 * PADK];   // 50176 B; aliased as f32 h2[64][H2S] later
    __shared__ int qi[64];
    float* h2 = (float*)hA;

    const int t = threadIdx.x;
    const int e0 = blockIdx.x * 64;
    const int lane = t & 63;
    const int w = t >> 6;                // 0..7
    const int ln = lane & 15;
    const int lq = lane >> 4;

    if (t < 64) qi[t] = edges[2 * (e0 + t)];

    // ---- gather h0 = gelu(pg[g] + pq[q]); thread t owns edge m=t>>3, chunk lane t&7 --
    {
        const int m = t >> 3;            // 0..63
        const int cl = t & 7;
        int2 eg = ((const int2*)edges)[e0 + m];     // {qidx, gidx}
        const half8* gsrc = (const half8*)(pg + (size_t)eg.y * 384) + cl;
        const half8* qsrc = (const half8*)(pq + (size_t)eg.x * 384) + cl;
        half8* dst = (half8*)(hA + m * PADK + cl * 8);
        #pragma unroll
        for (int i = 0; i < 6; ++i) {
            half8 va = gsrc[i * 8];
            half8 vb = qsrc[i * 8];
            half8 o;
            #pragma unroll
            for (int j = 0; j < 8; ++j)
                o[j] = (_Float16)gelu_f((float)va[j] + (float)vb[j]);
            dst[i * 8] = o;
        }
    }
    __syncthreads();

    // ---- layer 1: 384 -> 384, gelu, in-place. wave w owns 48-col output slice ----
    {
        f32x4 acc[4][3];
        #pragma unroll
        for (int nt = 0; nt < 3; ++nt) {
            f32x4 bv = *(const f32x4*)(b1 + w * 48 + nt * 16 + lq * 4);
            #pragma unroll
            for (int mt = 0; mt < 4; ++mt) acc[mt][nt] = bv;
        }
        #pragma unroll 2
        for (int ks = 0; ks < 12; ++ks) {
            half8 a[4], bf[3];
            #pragma unroll
            for (int mt = 0; mt < 4; ++mt)
                a[mt] = *(const half8*)(hA + (mt * 16 + ln) * PADK + ks * 32 + lq * 8);
            #pragma unroll
            for (int nt = 0; nt < 3; ++nt)
                bf[nt] = *(const half8*)(Wp1 + (size_t)(((w * 3 + nt) * 12 + ks) * 512 + lane * 8));
            #pragma unroll
            for (int nt = 0; nt < 3; ++nt)
                #pragma unroll
                for (int mt = 0; mt < 4; ++mt)
                    acc[mt][nt] = __builtin_amdgcn_mfma_f32_16x16x32_f16(bf[nt], a[mt], acc[mt][nt], 0, 0, 0);
        }
        __syncthreads();   // all waves done reading hA
        // lane holds h[m = mt*16+ln][n = w*48 + nt*16 + lq*4 + r] -> packed b64 writes
        #pragma unroll
        for (int mt = 0; mt < 4; ++mt)
            #pragma unroll
            for (int nt = 0; nt < 3; ++nt) {
                half4v hv;
                #pragma unroll
                for (int r = 0; r < 4; ++r) hv[r] = (_Float16)gelu_f(acc[mt][nt][r]);
                *(half4v*)(hA + (mt * 16 + ln) * PADK + w * 48 + nt * 16 + lq * 4) = hv;
            }
        __syncthreads();
    }

    // ---- layer 2: 384 -> 192. wave w: n-slice (w&3)*48, m-half (w>>2)*32 ----
    {
        const int n0 = (w & 3) * 48;
        const int mh = (w >> 2) * 2;                 // physical m-tile base
        f32x4 acc[2][3];
        #pragma unroll
        for (int nt = 0; nt < 3; ++nt) {
            f32x4 bv = *(const f32x4*)(b2 + n0 + nt * 16 + lq * 4);
            #pragma unroll
            for (int mt = 0; mt < 2; ++mt) acc[mt][nt] = bv;
        }
        #pragma unroll 2
        for (int ks = 0; ks < 12; ++ks) {
            half8 a[2], bf[3];
            #pragma unroll
            for (int mt = 0; mt < 2; ++mt)
                a[mt] = *(const half8*)(hA + ((mh + mt) * 16 + ln) * PADK + ks * 32 + lq * 8);
            #pragma unroll
            for (int nt = 0; nt < 3; ++nt)
                bf[nt] = *(const half8*)(Wp2 + (size_t)((((w & 3) * 3 + nt) * 12 + ks) * 512 + lane * 8));
            #pragma unroll
            for (int nt = 0; nt < 3; ++nt)
                #pragma unroll
                for (int mt = 0; mt < 2; ++mt)
                    acc[mt][nt] = __builtin_amdgcn_mfma_f32_16x16x32_f16(bf[nt], a[mt], acc[mt][nt], 0, 0, 0);
        }
        __syncthreads();   // all waves done reading hA; safe to overwrite as h2
        #pragma unroll
        for (int mt = 0; mt < 2; ++mt)
            #pragma unroll
            for (int nt = 0; nt < 3; ++nt)
                *(f32x4*)(h2 + ((mh + mt) * 16 + ln) * H2S + n0 + nt * 16 + lq * 4) = acc[mt][nt];
        __syncthreads();
    }

    // ---- segment reduce within block (qidx sorted), 2 row-halves, then atomics ----
    if (t < 384) {
        int half_ = t >= 192;
        int col = t - half_ * 192;
        int mlo = half_ * 32, mhi = mlo + 32;
        float a = 0.0f;
        for (int m = mlo; m < mhi; ++m) {
            a += h2[m * H2S + col];
            if (m == mhi - 1 || qi[m + 1] != qi[m]) {
                atomicAdd(&seg[(size_t)qi[m] * 192 + col], a);
                a = 0.0f;
            }
        }
    } else if (t < 386) {
        int half_ = t - 384;
        int mlo = half_ * 32, mhi = mlo + 32;
        float run = 1.0f;
        for (int m = mlo + 1; m < mhi; ++m) {
            if (qi[m] != qi[m - 1]) { atomicAdd(&cnt[qi[m - 1]], run); run = 1.0f; }
            else run += 1.0f;
        }
        atomicAdd(&cnt[qi[mhi - 1]], run);
    }
}

// ---------------- head: m = seg/max(cnt,1); out = gelu(m@W0+b0)@W1+b1 ----------------
#define PSK 196   // ps row stride (f32)

__global__ __launch_bounds__(256, 2) void head_kernel(
    const float* __restrict__ seg, const float* __restrict__ cnt,
    const _Float16* __restrict__ Wp0, const float* __restrict__ b0,
    const float* __restrict__ w1, const float* __restrict__ b1,
    float* __restrict__ out)
{
    __shared__ _Float16 hA[64 * PK];     // 25600 B
    __shared__ float ps[64 * PSK];       // 50176 B
    __shared__ float w1s[192 * 4];
    __shared__ float invc[64];
    const int t = threadIdx.x;
    const int r0 = blockIdx.x * 64;
    const int lane = t & 63;
    const int w = t >> 6;
    const int ln = lane & 15, lq = lane >> 4;

    if (t < 64) invc[t] = 1.0f / fmaxf(cnt[r0 + t], 1.0f);
    if (t < 192) ((float4*)w1s)[t] = ((const float4*)w1)[t];
    __syncthreads();

    #pragma unroll
    for (int i = 0; i < 12; ++i) {
        int idx = t + 256 * i;
        int r = idx / 48, c4 = idx - r * 48;
        float inv = invc[r];
        float4 v = ((const float4*)(seg + (size_t)(r0 + r) * 192))[c4];
        half4v hv; hv[0] = (_Float16)(v.x * inv); hv[1] = (_Float16)(v.y * inv);
        hv[2] = (_Float16)(v.z * inv); hv[3] = (_Float16)(v.w * inv);
        *(half4v*)(hA + r * PK + c4 * 4) = hv;
    }
    __syncthreads();

    f32x4 acc[4][3];
    #pragma unroll
    for (int nt = 0; nt < 3; ++nt) {
        f32x4 bv = *(const f32x4*)(b0 + w * 48 + nt * 16 + lq * 4);
        #pragma unroll
        for (int mt = 0; mt < 4; ++mt) acc[mt][nt] = bv;
    }
    #pragma unroll 2
    for (int ks = 0; ks < 6; ++ks) {
        half8 a[4], bf[3];
        #pragma unroll
        for (int mt = 0; mt < 4; ++mt)
            a[mt] = *(const half8*)(hA + (mt * 16 + ln) * PK + ks * 32 + lq * 8);
        #pragma unroll
        for (int nt = 0; nt < 3; ++nt)
            bf[nt] = *(const half8*)(Wp0 + (size_t)(((w * 3 + nt) * 6 + ks) * 512 + lane * 8));
        #pragma unroll
        for (int nt = 0; nt < 3; ++nt)
            #pragma unroll
            for (int mt = 0; mt < 4; ++mt)
                acc[mt][nt] = __builtin_amdgcn_mfma_f32_16x16x32_f16(bf[nt], a[mt], acc[mt][nt], 0, 0, 0);
    }
    // lane holds ps[m = mt*16+ln][n = w*48 + nt*16 + lq*4 + r] -> b128 LDS writes
    #pragma unroll
    for (int mt = 0; mt < 4; ++mt)
        #pragma unroll
        for (int nt = 0; nt < 3; ++nt) {
            f32x4 g;
            #pragma unroll
            for (int r = 0; r < 4; ++r) g[r] = gelu_f(acc[mt][nt][r]);
            *(f32x4*)(ps + (mt * 16 + ln) * PSK + w * 48 + nt * 16 + lq * 4) = g;
        }
    __syncthreads();

    // layer1: 192 -> 4, one thread per (row, out-col)
    {
        int r = t >> 2, oo = t & 3;
        float a = b1[oo];
        for (int k = 0; k < 192; ++k)
            a = fmaf(ps[r * PSK + k], w1s[k * 4 + oo], a);
        out[(size_t)(r0 + r) * 4 + oo] = a;
    }
}

extern "C" void kernel_launch(void* const* d_in, const int* in_sizes, int n_in,
                              void* d_out, int out_size, void* d_ws, size_t ws_size,
                              hipStream_t stream) {
    (void)in_sizes; (void)n_in; (void)out_size; (void)ws_size;
    const float* x       = (const float*)d_in[0];
    const float* qpos    = (const float*)d_in[1];
    const int*   edges   = (const int*)d_in[2];
    const float* proj_w  = (const float*)d_in[3];
    const float* proj_b  = (const float*)d_in[4];
    const float* msg0_w  = (const float*)d_in[5];
    const float* msg0_b  = (const float*)d_in[6];
    const float* msg1_w  = (const float*)d_in[7];
    const float* msg1_b  = (const float*)d_in[8];
    const float* msg2_w  = (const float*)d_in[9];
    const float* msg2_b  = (const float*)d_in[10];
    const float* pred0_w = (const float*)d_in[11];
    const float* pred0_b = (const float*)d_in[12];
    const float* pred1_w = (const float*)d_in[13];
    const float* pred1_b = (const float*)d_in[14];
    float* out = (float*)d_out;

    // ws layout (bytes):
    //  pg  f16: 25165824  @ 0
    //  pq  f16: 25165824  @ 25165824
    //  seg f32: 25165824  @ 50331648
    //  cnt f32:   131072  @ 75497472
    //  Wc  f32:   294912  @ 75628544
    //  bc  f32:     1536  @ 75923456
    //  WpC f16:   147456  @ 75924992
    //  WpQ f16:   147456  @ 76072448
    //  Wp1 f16:   294912  @ 76219904
    //  Wp2 f16:   147456  @ 76514816
    //  WpH f16:    73728  @ 76662272   (end 76736000)
    char* ws = (char*)d_ws;
    _Float16* pg  = (_Float16*)(ws);
    _Float16* pq  = (_Float16*)(ws + 25165824);
    float*    seg = (float*)(ws + 50331648);
    float*    cnt = (float*)(ws + 75497472);
    float*    Wc  = (float*)(ws + 75628544);
    float*    bc  = (float*)(ws + 75923456);
    _Float16* WpC = (_Float16*)(ws + 75924992);
    _Float16* WpQ = (_Float16*)(ws + 76072448);
    _Float16* Wp1 = (_Float16*)(ws + 76219904);
    _Float16* Wp2 = (_Float16*)(ws + 76514816);
    _Float16* WpH = (_Float16*)(ws + 76662272);

    hipMemsetAsync(seg, 0, 25165824 + 131072, stream);   // seg + cnt
    prep_kernel<<<290, 256, 0, stream>>>(proj_w, proj_b, msg0_w, msg0_b, Wc, bc);
    pack_all_kernel<<<198, 256, 0, stream>>>(Wc, WpC, msg0_w, WpQ,
                                             msg1_w, Wp1, msg2_w, Wp2,
                                             pred0_w, WpH);
    pg_kernel<<<512, 256, 0, stream>>>(x, WpC, bc, pg);
    pq_kernel<<<512, 256, 0, stream>>>(qpos, WpQ, pq);
    edge_mlp_kernel<<<4096, 512, 0, stream>>>(pg, pq, edges,
                                              Wp1, msg1_b, Wp2, msg2_b,
                                              seg, cnt);
    head_kernel<<<512, 256, 0, stream>>>(seg, cnt, WpH, pred0_b,
                                         pred1_w, pred1_b, out);
}